// Round 9
// baseline (212.107 us; speedup 1.0000x reference)
//
#include <hip/hip_runtime.h>
#include <hip/hip_bf16.h>
#include <math.h>
#include <stdint.h>

// Problem constants
#define BATCH 2
#define SEQ   1024
#define HID   2048
#define NH    16
#define NKV   4
#define HEAD  128
#define MROWS (BATCH*SEQ)      // 2048
#define QSC   0.08838834764831845f   // 1/sqrt(128), folded into Q in attn prologue

typedef _Float16 f16;
typedef _Float16 f16x8 __attribute__((ext_vector_type(8)));
typedef __fp16   h16x2 __attribute__((ext_vector_type(2)));   // cvt_pkrtz return type
typedef float    f32x4 __attribute__((ext_vector_type(4)));

// ---------------------------------------------------------------------------
// helpers
// ---------------------------------------------------------------------------
__device__ __forceinline__ void glds16(const void* g, void* l) {
    // async global->LDS, 16B per lane; LDS dest = wave-uniform base + lane*16
    __builtin_amdgcn_global_load_lds(
        (const __attribute__((address_space(1))) void*)g,
        (__attribute__((address_space(3))) void*)l, 16, 0, 0);
}

__device__ __forceinline__ f32x4 mfma16(f16x8 a, f16x8 b, f32x4 c) {
    return __builtin_amdgcn_mfma_f32_16x16x32_f16(a, b, c, 0, 0, 0);
}

// ---------------------------------------------------------------------------
// prep: fused  (a) x fp32->fp16   (blocks [0,4096))
//              (b) Wqkv transpose+convert -> Wqkvt[3072][2048]  ([4096,5632))
//              (c) Wo   transpose+convert -> Wot[2048][2048]    ([5632,6656))
// ---------------------------------------------------------------------------
__global__ __launch_bounds__(256)
void prep(const float* __restrict__ x,
          const float* __restrict__ wq, const float* __restrict__ wk,
          const float* __restrict__ wv, const float* __restrict__ wo,
          f16* __restrict__ x16, f16* __restrict__ Wqkvt, f16* __restrict__ Wot)
{
    __shared__ float t[64][65];
    const int bid = blockIdx.x, tid = threadIdx.x;
    if (bid < 4096) {
        int i = bid * 256 + tid;
        float4 v = ((const float4*)x)[i];
        union { ushort4 u; f16 h[4]; } o;
        o.h[0] = (f16)v.x; o.h[1] = (f16)v.y; o.h[2] = (f16)v.z; o.h[3] = (f16)v.w;
        ((ushort4*)x16)[i] = o.u;
        return;
    }
    const float* W; int ld, cs, k0, n0; f16* out;
    if (bid < 5632) {
        int b2 = bid - 4096;
        n0 = (b2 % 48) * 64; k0 = (b2 / 48) * 64; out = Wqkvt;
        if (n0 < 2048)      { W = wq; ld = 2048; cs = n0; }
        else if (n0 < 2560) { W = wk; ld = 512;  cs = n0 - 2048; }
        else                { W = wv; ld = 512;  cs = n0 - 2560; }
    } else {
        int b3 = bid - 5632;
        n0 = (b3 % 32) * 64; k0 = (b3 / 32) * 64; out = Wot;
        W = wo; ld = 2048; cs = n0;
    }
    const int tr = tid >> 4, tc = tid & 15;
    #pragma unroll
    for (int i = 0; i < 4; ++i) {
        int row = tr * 4 + i;  // k-row
        float4 v = *(const float4*)&W[(size_t)(k0 + row) * ld + cs + tc * 4];
        t[row][tc*4+0] = v.x; t[row][tc*4+1] = v.y;
        t[row][tc*4+2] = v.z; t[row][tc*4+3] = v.w;
    }
    __syncthreads();
    #pragma unroll
    for (int i = 0; i < 4; ++i) {
        int nrow = tr * 4 + i;
        union { ushort4 u; f16 h[4]; } o;
        o.h[0] = (f16)t[tc*4+0][nrow]; o.h[1] = (f16)t[tc*4+1][nrow];
        o.h[2] = (f16)t[tc*4+2][nrow]; o.h[3] = (f16)t[tc*4+3][nrow];
        *(ushort4*)&out[(size_t)(n0 + nrow) * 2048 + k0 + tc * 4] = o.u;
    }
}

// ---------------------------------------------------------------------------
// fp16 MFMA GEMM (round-8 version, kept): 128x64 tile, BK=64, 4 waves.
// 2-buffer counted-vmcnt pipeline; LDS 48KB; XCD-swizzled 1-D grid.
// MODE 1: raw fp16 q/k + transposed v. MODE 0: fp32 store.
// ---------------------------------------------------------------------------
template<int MODE>
__global__ __launch_bounds__(256)
void gemm16(const f16* __restrict__ A, const f16* __restrict__ Bt,
            f16* __restrict__ Oq, f16* __restrict__ Ok, f16* __restrict__ Ov,
            float* __restrict__ Of, int ntn)
{
    __shared__ f16 As[2][128 * 64];   // 16KB each
    __shared__ f16 Bs[2][64 * 64];    // 8KB each
    const int tid   = threadIdx.x;
    const int lane  = tid & 63;
    const int wid   = tid >> 6;
    const int col_l = lane & 15;
    const int hi    = lane >> 4;

    const int nwg = gridDim.x;
    const int cpx = nwg >> 3;
    const int bid = blockIdx.x;
    const int sw  = (bid & 7) * cpx + (bid >> 3);
    const int n0  = (sw % ntn) * 64;
    const int m0  = (sw / ntn) * 128;

    f32x4 acc[2][4];
    #pragma unroll
    for (int mt = 0; mt < 2; ++mt)
        #pragma unroll
        for (int nt = 0; nt < 4; ++nt)
            acc[mt][nt] = (f32x4){0.f, 0.f, 0.f, 0.f};

    auto stage = [&](int buf, int kt) {
        #pragma unroll
        for (int j = 0; j < 4; ++j) {                  // A: 128 rows x 8 granules
            int gidx = j * 256 + tid;
            int r = gidx >> 3, g = gidx & 7;
            int gs = (g ^ (r & 7)) << 3;
            glds16(A + (size_t)(m0 + r) * 2048 + kt * 64 + gs,
                   (char*)&As[buf][0] + (size_t)(j * 256 + (wid << 6)) * 16);
        }
        #pragma unroll
        for (int j = 0; j < 2; ++j) {                  // B: 64 rows x 8 granules
            int gidx = j * 256 + tid;
            int r = gidx >> 3, g = gidx & 7;
            int gs = (g ^ (r & 7)) << 3;
            glds16(Bt + (size_t)(n0 + r) * 2048 + kt * 64 + gs,
                   (char*)&Bs[buf][0] + (size_t)(j * 256 + (wid << 6)) * 16);
        }
    };

    stage(0, 0);
    stage(1, 1);

    const int ar0 = wid * 32 + col_l;
    const int ar1 = ar0 + 16;

    int cur = 0;
    #pragma unroll 1
    for (int kt = 0; kt < 32; ++kt) {
        if (kt < 31) asm volatile("s_waitcnt vmcnt(6)" ::: "memory");
        else         asm volatile("s_waitcnt vmcnt(0)" ::: "memory");
        __builtin_amdgcn_s_barrier();
        __builtin_amdgcn_sched_barrier(0);

        #pragma unroll
        for (int ks = 0; ks < 2; ++ks) {
            int gr = (ks << 2) | hi;
            f16x8 a0 = *(const f16x8*)&As[cur][ar0 * 64 + ((gr ^ (ar0 & 7)) << 3)];
            f16x8 a1 = *(const f16x8*)&As[cur][ar1 * 64 + ((gr ^ (ar1 & 7)) << 3)];
            #pragma unroll
            for (int nt = 0; nt < 4; ++nt) {
                int br = nt * 16 + col_l;
                f16x8 b = *(const f16x8*)&Bs[cur][br * 64 + ((gr ^ (br & 7)) << 3)];
                acc[0][nt] = mfma16(a0, b, acc[0][nt]);
                acc[1][nt] = mfma16(a1, b, acc[1][nt]);
            }
        }

        asm volatile("s_waitcnt lgkmcnt(0)" ::: "memory");
        __builtin_amdgcn_sched_barrier(0);
        __builtin_amdgcn_s_barrier();
        if (kt + 2 < 32) stage(cur, kt + 2);
        cur ^= 1;
    }

    if (MODE == 0) {
        #pragma unroll
        for (int mt = 0; mt < 2; ++mt)
            #pragma unroll
            for (int r = 0; r < 4; ++r) {
                int grow = m0 + wid * 32 + mt * 16 + hi * 4 + r;
                #pragma unroll
                for (int nt = 0; nt < 4; ++nt)
                    Of[(size_t)grow * 2048 + n0 + nt * 16 + col_l] = acc[mt][nt][r];
            }
    } else if (n0 < 2048) {            // q raw fp16
        #pragma unroll
        for (int mt = 0; mt < 2; ++mt)
            #pragma unroll
            for (int r = 0; r < 4; ++r) {
                int grow = m0 + wid * 32 + mt * 16 + hi * 4 + r;
                #pragma unroll
                for (int nt = 0; nt < 4; ++nt)
                    Oq[(size_t)grow * 2048 + n0 + nt * 16 + col_l] = (f16)acc[mt][nt][r];
            }
    } else if (n0 < 2560) {            // k raw fp16
        #pragma unroll
        for (int mt = 0; mt < 2; ++mt)
            #pragma unroll
            for (int r = 0; r < 4; ++r) {
                int grow = m0 + wid * 32 + mt * 16 + hi * 4 + r;
                #pragma unroll
                for (int nt = 0; nt < 4; ++nt)
                    Ok[(size_t)grow * 512 + (n0 - 2048) + nt * 16 + col_l] = (f16)acc[mt][nt][r];
            }
    } else {                           // v: write transposed vT[(b*4+kv)*128+d][1024]
        #pragma unroll
        for (int mt = 0; mt < 2; ++mt) {
            int grow0 = m0 + wid * 32 + mt * 16 + hi * 4;
            int bb = grow0 >> 10, s0 = grow0 & (SEQ - 1);
            #pragma unroll
            for (int nt = 0; nt < 4; ++nt) {
                int vcol = (n0 - 2560) + nt * 16 + col_l;
                int kvh = vcol >> 7, d = vcol & 127;
                union { ushort4 u; f16 h[4]; } pv;
                #pragma unroll
                for (int r = 0; r < 4; ++r) pv.h[r] = (f16)acc[mt][nt][r];
                *(ushort4*)&Ov[(size_t)((bb * 4 + kvh) * 128 + d) * 1024 + s0] = pv.u;
            }
        }
    }
}

// ---------------------------------------------------------------------------
// In-place RoPE on k16 [2048][512] only (Q is roped in attn prologue).
// ---------------------------------------------------------------------------
__global__ __launch_bounds__(256)
void rope_k(f16* __restrict__ k16,
            const float* __restrict__ cosp, const float* __restrict__ sinp)
{
    int t = blockIdx.x * 256 + threadIdx.x;          // 131072 threads
    int row = t >> 6; int rem = t & 63; int head = rem >> 4; int quad = rem & 15;
    f16* p = k16 + (size_t)row * 512 + head * 128 + quad * 4;
    const int srow = row & (SEQ - 1);
    const int d0 = quad * 4;
    float4 c4 = *(const float4*)&cosp[srow * HEAD + d0];
    float4 s4 = *(const float4*)&sinp[srow * HEAD + d0];
    union { ushort4 u; f16 h[4]; } lo, hv, olo, ohi;
    lo.u = *(ushort4*)p;
    hv.u = *(ushort4*)(p + 64);
    const float c[4] = {c4.x, c4.y, c4.z, c4.w};
    const float s[4] = {s4.x, s4.y, s4.z, s4.w};
    #pragma unroll
    for (int e = 0; e < 4; ++e) {
        float fl = (float)lo.h[e], fh = (float)hv.h[e];
        olo.h[e] = (f16)(fl * c[e] - fh * s[e]);
        ohi.h[e] = (f16)(fh * c[e] + fl * s[e]);
    }
    *(ushort4*)p        = olo.u;
    *(ushort4*)(p + 64) = ohi.u;
}

// ---------------------------------------------------------------------------
// MFMA flash attention v3 (causal, GQA). KVBLK=64, block = 128 thr = 2 waves,
// each wave owns 32 q-rows (2 groups of 16) -> K/V fragment reads shared
// across both groups: LDS-read bytes per q-row HALVED vs 4x16 layout.
// Defer-max (THR=8): skip O-rescale + corr broadcast when tile max is within
// 8 of running max (wave-uniform test). setprio(1) around MFMA clusters.
// Pair schedule: bx and bx+256 get qt = 15-j and j -> uniform per-CU work.
// ---------------------------------------------------------------------------
__global__ __launch_bounds__(128)
void attn16(const f16* __restrict__ q16, const f16* __restrict__ k16,
            const f16* __restrict__ vT,
            const float* __restrict__ cosp, const float* __restrict__ sinp,
            f16* __restrict__ attnb)
{
    __shared__ f16 Ks[2][64 * 128];   // 16KB each
    __shared__ f16 Vs[2][128 * 64];   // 16KB each

    const int tid   = threadIdx.x;
    const int lane  = tid & 63;
    const int wid   = tid >> 6;       // 0..1
    const int col_l = lane & 15;
    const int hi    = lane >> 4;

    const int bx = blockIdx.x;
    const int r8 = bx >> 8;              // 0 = heavy round, 1 = light round
    const int c  = bx & 255;
    const int bh = c >> 3;
    const int j8 = c & 7;
    const int qt = r8 ? j8 : (15 - j8);  // pair {15-j, j}: 17 tiles per CU
    const int b  = bh >> 4;
    const int h  = bh & 15;
    const int kv = h >> 2;
    const int qbase = qt * 64 + wid * 32;

    // ---- Q load + in-register RoPE + scale for both 16-row groups ----
    f16x8 qf[2][4];
    #pragma unroll
    for (int g = 0; g < 2; ++g) {
        const int qrow = qbase + g * 16 + col_l;
        const f16* qp = q16 + (size_t)(b * SEQ + qrow) * 2048 + h * 128 + hi * 8;
        f16x8 raw[4];
        #pragma unroll
        for (int ks = 0; ks < 4; ++ks) raw[ks] = *(const f16x8*)&qp[ks * 32];
        #pragma unroll
        for (int ks = 0; ks < 2; ++ks) {
            union { float4 v; float a[4]; } c0, c1, s0, s1;
            const float* cp = cosp + qrow * HEAD + ks * 32 + hi * 8;
            const float* sp = sinp + qrow * HEAD + ks * 32 + hi * 8;
            c0.v = *(const float4*)cp;  c1.v = *(const float4*)(cp + 4);
            s0.v = *(const float4*)sp;  s1.v = *(const float4*)(sp + 4);
            #pragma unroll
            for (int e = 0; e < 8; ++e) {
                float cc = (e < 4) ? c0.a[e & 3] : c1.a[e & 3];
                float sv = (e < 4) ? s0.a[e & 3] : s1.a[e & 3];
                float lo = (float)raw[ks][e], hv = (float)raw[ks + 2][e];
                qf[g][ks][e]     = (f16)((lo * cc - hv * sv) * QSC);
                qf[g][ks + 2][e] = (f16)((hv * cc + lo * sv) * QSC);
            }
        }
    }
    const f16* vTg = vT + (size_t)(b * 4 + kv) * 128 * 1024;

    auto stage = [&](int buf, int kt) {
        #pragma unroll
        for (int j = 0; j < 8; ++j) {          // K: 64 rows x 16 granules
            int gidx = j * 128 + tid;
            int r = gidx >> 4, g = gidx & 15;
            glds16(k16 + (size_t)(b * SEQ + kt * 64 + r) * 512 + kv * 128 + ((g ^ (r & 7)) << 3),
                   (char*)&Ks[buf][0] + (size_t)(j * 128 + (wid << 6)) * 16);
        }
        #pragma unroll
        for (int j = 0; j < 8; ++j) {          // V: 128 d-rows x 8 granules
            int gidx = j * 128 + tid;
            int d = gidx >> 3, g = gidx & 7;
            glds16(vTg + (size_t)d * 1024 + kt * 64 + ((g ^ (d & 7)) << 3),
                   (char*)&Vs[buf][0] + (size_t)(j * 128 + (wid << 6)) * 16);
        }
    };

    f32x4 O[2][8];
    #pragma unroll
    for (int g = 0; g < 2; ++g)
        #pragma unroll
        for (int dt = 0; dt < 8; ++dt) O[g][dt] = (f32x4){0.f, 0.f, 0.f, 0.f};
    float m0 = -INFINITY, m1 = -INFINITY, l0 = 0.f, l1 = 0.f;

    const int ntiles = qt + 1;
    stage(0, 0);
    asm volatile("s_waitcnt vmcnt(0)" ::: "memory");
    __syncthreads();

    int cur = 0;
    #pragma unroll 1
    for (int kt = 0; kt < ntiles; ++kt) {
        if (kt + 1 < ntiles) stage(cur ^ 1, kt + 1);

        // ---- S^T = K . Q^T : K-fragments read ONCE, used by both groups ----
        f32x4 S0[4], S1[4];
        #pragma unroll
        for (int t = 0; t < 4; ++t) {
            S0[t] = (f32x4){0.f, 0.f, 0.f, 0.f};
            S1[t] = (f32x4){0.f, 0.f, 0.f, 0.f};
        }
        __builtin_amdgcn_s_setprio(1);
        #pragma unroll
        for (int ks = 0; ks < 4; ++ks) {
            int gr = (ks << 2) | hi;
            #pragma unroll
            for (int t = 0; t < 4; ++t) {
                int rr = t * 16 + col_l;
                f16x8 kf = *(const f16x8*)&Ks[cur][rr * 128 + ((gr ^ (rr & 7)) << 3)];
                S0[t] = mfma16(kf, qf[0][ks], S0[t]);
                S1[t] = mfma16(kf, qf[1][ks], S1[t]);
            }
        }
        __builtin_amdgcn_s_setprio(0);

        float p0[16], p1[16];
        #pragma unroll
        for (int t = 0; t < 4; ++t)
            #pragma unroll
            for (int r = 0; r < 4; ++r) {
                p0[t*4+r] = S0[t][r];
                p1[t*4+r] = S1[t][r];
            }

        // causal mask (diagonal tile only): k = kt*64 + (sl>>2)*16 + hi*4 + (sl&3)
        if (kt == qt) {
            #pragma unroll
            for (int sl = 0; sl < 16; ++sl) {
                int kk = kt * 64 + (sl >> 2) * 16 + hi * 4 + (sl & 3);
                if (kk > qbase + col_l)      p0[sl] = -INFINITY;
                if (kk > qbase + 16 + col_l) p1[sl] = -INFINITY;
            }
        }

        // ---- online softmax, two independent chains, defer-max THR=8 ----
        float pm0 = p0[0], pm1 = p1[0];
        #pragma unroll
        for (int sl = 1; sl < 16; ++sl) { pm0 = fmaxf(pm0, p0[sl]); pm1 = fmaxf(pm1, p1[sl]); }
        pm0 = fmaxf(pm0, __shfl_xor(pm0, 16)); pm1 = fmaxf(pm1, __shfl_xor(pm1, 16));
        pm0 = fmaxf(pm0, __shfl_xor(pm0, 32)); pm1 = fmaxf(pm1, __shfl_xor(pm1, 32));

        const bool skip = __all((pm0 <= m0 + 8.f) && (pm1 <= m1 + 8.f));
        if (!skip) {
            float mn0 = fmaxf(m0, pm0), mn1 = fmaxf(m1, pm1);
            float corr0 = __expf(m0 - mn0), corr1 = __expf(m1 - mn1);
            m0 = mn0; m1 = mn1;
            float cb0[4], cb1[4];
            #pragma unroll
            for (int r = 0; r < 4; ++r) {
                cb0[r] = __int_as_float(__builtin_amdgcn_ds_bpermute((hi * 4 + r) << 2,
                                                                     __float_as_int(corr0)));
                cb1[r] = __int_as_float(__builtin_amdgcn_ds_bpermute((hi * 4 + r) << 2,
                                                                     __float_as_int(corr1)));
            }
            #pragma unroll
            for (int dt = 0; dt < 8; ++dt)
                #pragma unroll
                for (int r = 0; r < 4; ++r) {
                    O[0][dt][r] *= cb0[r];
                    O[1][dt][r] *= cb1[r];
                }
            l0 *= corr0; l1 *= corr1;
        }

        float ps0 = 0.f, ps1 = 0.f;
        #pragma unroll
        for (int sl = 0; sl < 16; ++sl) {
            p0[sl] = __expf(p0[sl] - m0); ps0 += p0[sl];
            p1[sl] = __expf(p1[sl] - m1); ps1 += p1[sl];
        }
        ps0 += __shfl_xor(ps0, 16); ps1 += __shfl_xor(ps1, 16);
        ps0 += __shfl_xor(ps0, 32); ps1 += __shfl_xor(ps1, 32);
        l0 += ps0; l1 += ps1;

        // ---- repack P into A-fragments (per group, k-halves 0..31 / 32..63) ----
        union U2 { h16x2 h; int i; };
        int pk0[8], pk1[8];
        #pragma unroll
        for (int t = 0; t < 4; ++t) {
            { U2 u; u.h = __builtin_amdgcn_cvt_pkrtz(p0[t*4+0], p0[t*4+1]); pk0[t*2+0] = u.i; }
            { U2 u; u.h = __builtin_amdgcn_cvt_pkrtz(p0[t*4+2], p0[t*4+3]); pk0[t*2+1] = u.i; }
            { U2 u; u.h = __builtin_amdgcn_cvt_pkrtz(p1[t*4+0], p1[t*4+1]); pk1[t*2+0] = u.i; }
            { U2 u; u.h = __builtin_amdgcn_cvt_pkrtz(p1[t*4+2], p1[t*4+3]); pk1[t*2+1] = u.i; }
        }
        union UA { f16x8 v; int i[4]; } F0a, F0b, F1a, F1b;
        #pragma unroll
        for (int j = 0; j < 4; ++j) {
            int srcl = col_l + 16 * ((2 * hi + (j >> 1)) & 3);
            int a0 = __builtin_amdgcn_ds_bpermute(srcl << 2, pk0[j & 1]);
            int a1 = __builtin_amdgcn_ds_bpermute(srcl << 2, pk0[2 + (j & 1)]);
            F0a.i[j] = (hi >= 2) ? a1 : a0;
            int b0 = __builtin_amdgcn_ds_bpermute(srcl << 2, pk0[4 + (j & 1)]);
            int b1 = __builtin_amdgcn_ds_bpermute(srcl << 2, pk0[6 + (j & 1)]);
            F0b.i[j] = (hi >= 2) ? b1 : b0;
            int c0 = __builtin_amdgcn_ds_bpermute(srcl << 2, pk1[j & 1]);
            int c1 = __builtin_amdgcn_ds_bpermute(srcl << 2, pk1[2 + (j & 1)]);
            F1a.i[j] = (hi >= 2) ? c1 : c0;
            int d0 = __builtin_amdgcn_ds_bpermute(srcl << 2, pk1[4 + (j & 1)]);
            int d1 = __builtin_amdgcn_ds_bpermute(srcl << 2, pk1[6 + (j & 1)]);
            F1b.i[j] = (hi >= 2) ? d1 : d0;
        }

        // ---- O += P @ V : V-fragments read ONCE, used by both groups ----
        __builtin_amdgcn_s_setprio(1);
        #pragma unroll
        for (int dt = 0; dt < 8; ++dt) {
            int vr = dt * 16 + col_l;
            f16x8 v0 = *(const f16x8*)&Vs[cur][vr * 64 + ((hi ^ (vr & 7)) << 3)];
            f16x8 v1 = *(const f16x8*)&Vs[cur][vr * 64 + (((4 | hi) ^ (vr & 7)) << 3)];
            O[0][dt] = mfma16(F0a.v, v0, O[0][dt]);
            O[0][dt] = mfma16(F0b.v, v1, O[0][dt]);
            O[1][dt] = mfma16(F1a.v, v0, O[1][dt]);
            O[1][dt] = mfma16(F1b.v, v1, O[1][dt]);
        }
        __builtin_amdgcn_s_setprio(0);

        if (kt + 1 < ntiles) {
            asm volatile("s_waitcnt vmcnt(0)" ::: "memory");
            __syncthreads();
            cur ^= 1;
        }
    }

    // ---- finalize: broadcast 1/l to acc-row layout, store fp16 ----
    float li0 = 1.f / l0, li1 = 1.f / l1;
    float lb0[4], lb1[4];
    #pragma unroll
    for (int r = 0; r < 4; ++r) {
        lb0[r] = __int_as_float(__builtin_amdgcn_ds_bpermute((hi * 4 + r) << 2,
                                                             __float_as_int(li0)));
        lb1[r] = __int_as_float(__builtin_amdgcn_ds_bpermute((hi * 4 + r) << 2,
                                                             __float_as_int(li1)));
    }
    #pragma unroll
    for (int dt = 0; dt < 8; ++dt)
        #pragma unroll
        for (int r = 0; r < 4; ++r) {
            int row0 = b * SEQ + qbase + hi * 4 + r;
            attnb[(size_t)row0 * 2048 + h * 128 + dt * 16 + col_l]        = (f16)(O[0][dt][r] * lb0[r]);
            attnb[(size_t)(row0 + 16) * 2048 + h * 128 + dt * 16 + col_l] = (f16)(O[1][dt][r] * lb1[r]);
        }
}

// ---------------------------------------------------------------------------
extern "C" void kernel_launch(void* const* d_in, const int* in_sizes, int n_in,
                              void* d_out, int out_size, void* d_ws, size_t ws_size,
                              hipStream_t stream)
{
    const float* x    = (const float*)d_in[0];
    const float* cosp = (const float*)d_in[1];
    const float* sinp = (const float*)d_in[2];
    const float* wq   = (const float*)d_in[3];
    const float* wk   = (const float*)d_in[4];
    const float* wv   = (const float*)d_in[5];
    const float* wo   = (const float*)d_in[6];
    float* out = (float*)d_out;

    // workspace layout (40 MiB):
    //   [0,        8388608)  x16    (fp16 x) -> reused as attn out after GEMM1
    //   [8388608, 20971520)  Wqkvt  (fp16 [3072][2048])
    //   [20971520,29360128)  q16    (fp16 [2048][2048], raw; roped in attn)
    //   [29360128,31457280)  k16    (fp16 [2048][512], raw then roped in place)
    //   [31457280,33554432)  vT     (fp16 [(b*4+kv)*128+d][1024])
    //   [33554432,41943040)  Wot    (fp16 [2048][2048])
    char* ws = (char*)d_ws;
    f16* x16    = (f16*)(ws);
    f16* attn16v= (f16*)(ws);                 // overlay (x dead after GEMM1)
    f16* Wqkvt  = (f16*)(ws + 8388608);
    f16* q16    = (f16*)(ws + 20971520);
    f16* k16    = (f16*)(ws + 29360128);
    f16* vT     = (f16*)(ws + 31457280);
    f16* Wot    = (f16*)(ws + 33554432);

    // 1. fused prep: cvt x + transpose Wqkv + transpose Wo
    prep<<<6656, 256, 0, stream>>>(x, wq, wk, wv, wo, x16, Wqkvt, Wot);

    // 2. fused QKV projection (raw q/k fp16, v transposed); 768 blk = 3/CU
    gemm16<1><<<768, 256, 0, stream>>>(x16, Wqkvt, q16, k16, vT, nullptr, 48);

    // 3. in-place RoPE on K only
    rope_k<<<512, 256, 0, stream>>>(k16, cosp, sinp);

    // 4. causal GQA MFMA flash attention v3 -> attn16 (overlays x16)
    attn16<<<512, 128, 0, stream>>>(q16, k16, vT, cosp, sinp, attn16v);

    // 5. output projection (fp32 out); 512 blk = 2/CU
    gemm16<0><<<512, 256, 0, stream>>>(attn16v, Wot, nullptr, nullptr, nullptr, out, 32);
}

// Round 10
// 200.909 us; speedup vs baseline: 1.0557x; 1.0557x over previous
//
#include <hip/hip_runtime.h>
#include <hip/hip_bf16.h>
#include <math.h>
#include <stdint.h>

// Problem constants
#define BATCH 2
#define SEQ   1024
#define HID   2048
#define NH    16
#define NKV   4
#define HEAD  128
#define MROWS (BATCH*SEQ)      // 2048
#define QSC   0.08838834764831845f   // 1/sqrt(128), folded into Q in attn prologue

typedef _Float16 f16;
typedef _Float16 f16x8 __attribute__((ext_vector_type(8)));
typedef __fp16   h16x2 __attribute__((ext_vector_type(2)));   // cvt_pkrtz return type
typedef float    f32x4 __attribute__((ext_vector_type(4)));

// ---------------------------------------------------------------------------
// helpers
// ---------------------------------------------------------------------------
__device__ __forceinline__ void glds16(const void* g, void* l) {
    // async global->LDS, 16B per lane; LDS dest = wave-uniform base + lane*16
    __builtin_amdgcn_global_load_lds(
        (const __attribute__((address_space(1))) void*)g,
        (__attribute__((address_space(3))) void*)l, 16, 0, 0);
}

__device__ __forceinline__ f32x4 mfma16(f16x8 a, f16x8 b, f32x4 c) {
    return __builtin_amdgcn_mfma_f32_16x16x32_f16(a, b, c, 0, 0, 0);
}

// ---------------------------------------------------------------------------
// prep: fused  (a) x fp32->fp16   (blocks [0,4096))
//              (b) Wqkv transpose+convert -> Wqkvt[3072][2048]  ([4096,5632))
//              (c) Wo   transpose+convert -> Wot[2048][2048]    ([5632,6656))
// ---------------------------------------------------------------------------
__global__ __launch_bounds__(256)
void prep(const float* __restrict__ x,
          const float* __restrict__ wq, const float* __restrict__ wk,
          const float* __restrict__ wv, const float* __restrict__ wo,
          f16* __restrict__ x16, f16* __restrict__ Wqkvt, f16* __restrict__ Wot)
{
    __shared__ float t[64][65];
    const int bid = blockIdx.x, tid = threadIdx.x;
    if (bid < 4096) {
        int i = bid * 256 + tid;
        float4 v = ((const float4*)x)[i];
        union { ushort4 u; f16 h[4]; } o;
        o.h[0] = (f16)v.x; o.h[1] = (f16)v.y; o.h[2] = (f16)v.z; o.h[3] = (f16)v.w;
        ((ushort4*)x16)[i] = o.u;
        return;
    }
    const float* W; int ld, cs, k0, n0; f16* out;
    if (bid < 5632) {
        int b2 = bid - 4096;
        n0 = (b2 % 48) * 64; k0 = (b2 / 48) * 64; out = Wqkvt;
        if (n0 < 2048)      { W = wq; ld = 2048; cs = n0; }
        else if (n0 < 2560) { W = wk; ld = 512;  cs = n0 - 2048; }
        else                { W = wv; ld = 512;  cs = n0 - 2560; }
    } else {
        int b3 = bid - 5632;
        n0 = (b3 % 32) * 64; k0 = (b3 / 32) * 64; out = Wot;
        W = wo; ld = 2048; cs = n0;
    }
    const int tr = tid >> 4, tc = tid & 15;
    #pragma unroll
    for (int i = 0; i < 4; ++i) {
        int row = tr * 4 + i;  // k-row
        float4 v = *(const float4*)&W[(size_t)(k0 + row) * ld + cs + tc * 4];
        t[row][tc*4+0] = v.x; t[row][tc*4+1] = v.y;
        t[row][tc*4+2] = v.z; t[row][tc*4+3] = v.w;
    }
    __syncthreads();
    #pragma unroll
    for (int i = 0; i < 4; ++i) {
        int nrow = tr * 4 + i;
        union { ushort4 u; f16 h[4]; } o;
        o.h[0] = (f16)t[tc*4+0][nrow]; o.h[1] = (f16)t[tc*4+1][nrow];
        o.h[2] = (f16)t[tc*4+2][nrow]; o.h[3] = (f16)t[tc*4+3][nrow];
        *(ushort4*)&out[(size_t)(n0 + nrow) * 2048 + k0 + tc * 4] = o.u;
    }
}

// ---------------------------------------------------------------------------
// fp16 MFMA GEMM (round-8 version, kept): 128x64 tile, BK=64, 4 waves.
// 2-buffer counted-vmcnt pipeline; LDS 48KB; XCD-swizzled 1-D grid.
// MODE 1: raw fp16 q/k + transposed v. MODE 0: fp32 store.
// ---------------------------------------------------------------------------
template<int MODE>
__global__ __launch_bounds__(256)
void gemm16(const f16* __restrict__ A, const f16* __restrict__ Bt,
            f16* __restrict__ Oq, f16* __restrict__ Ok, f16* __restrict__ Ov,
            float* __restrict__ Of, int ntn)
{
    __shared__ f16 As[2][128 * 64];   // 16KB each
    __shared__ f16 Bs[2][64 * 64];    // 8KB each
    const int tid   = threadIdx.x;
    const int lane  = tid & 63;
    const int wid   = tid >> 6;
    const int col_l = lane & 15;
    const int hi    = lane >> 4;

    const int nwg = gridDim.x;
    const int cpx = nwg >> 3;
    const int bid = blockIdx.x;
    const int sw  = (bid & 7) * cpx + (bid >> 3);
    const int n0  = (sw % ntn) * 64;
    const int m0  = (sw / ntn) * 128;

    f32x4 acc[2][4];
    #pragma unroll
    for (int mt = 0; mt < 2; ++mt)
        #pragma unroll
        for (int nt = 0; nt < 4; ++nt)
            acc[mt][nt] = (f32x4){0.f, 0.f, 0.f, 0.f};

    auto stage = [&](int buf, int kt) {
        #pragma unroll
        for (int j = 0; j < 4; ++j) {                  // A: 128 rows x 8 granules
            int gidx = j * 256 + tid;
            int r = gidx >> 3, g = gidx & 7;
            int gs = (g ^ (r & 7)) << 3;
            glds16(A + (size_t)(m0 + r) * 2048 + kt * 64 + gs,
                   (char*)&As[buf][0] + (size_t)(j * 256 + (wid << 6)) * 16);
        }
        #pragma unroll
        for (int j = 0; j < 2; ++j) {                  // B: 64 rows x 8 granules
            int gidx = j * 256 + tid;
            int r = gidx >> 3, g = gidx & 7;
            int gs = (g ^ (r & 7)) << 3;
            glds16(Bt + (size_t)(n0 + r) * 2048 + kt * 64 + gs,
                   (char*)&Bs[buf][0] + (size_t)(j * 256 + (wid << 6)) * 16);
        }
    };

    stage(0, 0);
    stage(1, 1);

    const int ar0 = wid * 32 + col_l;
    const int ar1 = ar0 + 16;

    int cur = 0;
    #pragma unroll 1
    for (int kt = 0; kt < 32; ++kt) {
        if (kt < 31) asm volatile("s_waitcnt vmcnt(6)" ::: "memory");
        else         asm volatile("s_waitcnt vmcnt(0)" ::: "memory");
        __builtin_amdgcn_s_barrier();
        __builtin_amdgcn_sched_barrier(0);

        #pragma unroll
        for (int ks = 0; ks < 2; ++ks) {
            int gr = (ks << 2) | hi;
            f16x8 a0 = *(const f16x8*)&As[cur][ar0 * 64 + ((gr ^ (ar0 & 7)) << 3)];
            f16x8 a1 = *(const f16x8*)&As[cur][ar1 * 64 + ((gr ^ (ar1 & 7)) << 3)];
            #pragma unroll
            for (int nt = 0; nt < 4; ++nt) {
                int br = nt * 16 + col_l;
                f16x8 b = *(const f16x8*)&Bs[cur][br * 64 + ((gr ^ (br & 7)) << 3)];
                acc[0][nt] = mfma16(a0, b, acc[0][nt]);
                acc[1][nt] = mfma16(a1, b, acc[1][nt]);
            }
        }

        asm volatile("s_waitcnt lgkmcnt(0)" ::: "memory");
        __builtin_amdgcn_sched_barrier(0);
        __builtin_amdgcn_s_barrier();
        if (kt + 2 < 32) stage(cur, kt + 2);
        cur ^= 1;
    }

    if (MODE == 0) {
        #pragma unroll
        for (int mt = 0; mt < 2; ++mt)
            #pragma unroll
            for (int r = 0; r < 4; ++r) {
                int grow = m0 + wid * 32 + mt * 16 + hi * 4 + r;
                #pragma unroll
                for (int nt = 0; nt < 4; ++nt)
                    Of[(size_t)grow * 2048 + n0 + nt * 16 + col_l] = acc[mt][nt][r];
            }
    } else if (n0 < 2048) {            // q raw fp16
        #pragma unroll
        for (int mt = 0; mt < 2; ++mt)
            #pragma unroll
            for (int r = 0; r < 4; ++r) {
                int grow = m0 + wid * 32 + mt * 16 + hi * 4 + r;
                #pragma unroll
                for (int nt = 0; nt < 4; ++nt)
                    Oq[(size_t)grow * 2048 + n0 + nt * 16 + col_l] = (f16)acc[mt][nt][r];
            }
    } else if (n0 < 2560) {            // k raw fp16
        #pragma unroll
        for (int mt = 0; mt < 2; ++mt)
            #pragma unroll
            for (int r = 0; r < 4; ++r) {
                int grow = m0 + wid * 32 + mt * 16 + hi * 4 + r;
                #pragma unroll
                for (int nt = 0; nt < 4; ++nt)
                    Ok[(size_t)grow * 512 + (n0 - 2048) + nt * 16 + col_l] = (f16)acc[mt][nt][r];
            }
    } else {                           // v: write transposed vT[(b*4+kv)*128+d][1024]
        #pragma unroll
        for (int mt = 0; mt < 2; ++mt) {
            int grow0 = m0 + wid * 32 + mt * 16 + hi * 4;
            int bb = grow0 >> 10, s0 = grow0 & (SEQ - 1);
            #pragma unroll
            for (int nt = 0; nt < 4; ++nt) {
                int vcol = (n0 - 2560) + nt * 16 + col_l;
                int kvh = vcol >> 7, d = vcol & 127;
                union { ushort4 u; f16 h[4]; } pv;
                #pragma unroll
                for (int r = 0; r < 4; ++r) pv.h[r] = (f16)acc[mt][nt][r];
                *(ushort4*)&Ov[(size_t)((bb * 4 + kvh) * 128 + d) * 1024 + s0] = pv.u;
            }
        }
    }
}

// ---------------------------------------------------------------------------
// In-place RoPE on k16 [2048][512] only (Q is roped in attn prologue).
// ---------------------------------------------------------------------------
__global__ __launch_bounds__(256)
void rope_k(f16* __restrict__ k16,
            const float* __restrict__ cosp, const float* __restrict__ sinp)
{
    int t = blockIdx.x * 256 + threadIdx.x;          // 131072 threads
    int row = t >> 6; int rem = t & 63; int head = rem >> 4; int quad = rem & 15;
    f16* p = k16 + (size_t)row * 512 + head * 128 + quad * 4;
    const int srow = row & (SEQ - 1);
    const int d0 = quad * 4;
    float4 c4 = *(const float4*)&cosp[srow * HEAD + d0];
    float4 s4 = *(const float4*)&sinp[srow * HEAD + d0];
    union { ushort4 u; f16 h[4]; } lo, hv, olo, ohi;
    lo.u = *(ushort4*)p;
    hv.u = *(ushort4*)(p + 64);
    const float c[4] = {c4.x, c4.y, c4.z, c4.w};
    const float s[4] = {s4.x, s4.y, s4.z, s4.w};
    #pragma unroll
    for (int e = 0; e < 4; ++e) {
        float fl = (float)lo.h[e], fh = (float)hv.h[e];
        olo.h[e] = (f16)(fl * c[e] - fh * s[e]);
        ohi.h[e] = (f16)(fh * c[e] + fl * s[e]);
    }
    *(ushort4*)p        = olo.u;
    *(ushort4*)(p + 64) = ohi.u;
}

// ---------------------------------------------------------------------------
// MFMA flash attention v2+ (causal, GQA). KVBLK=64, 256 thr = 4 waves (16
// q-rows each) -> 8 waves/CU at 64KB LDS (the occupancy that round-9's v3
// lost). Adds: defer-max (THR=8) skipping the O-rescale chain on ~95% of
// tiles, and setprio(1) around both MFMA clusters.
// Pair schedule: bx and bx+256 get qt = 15-j and j -> uniform per-CU work.
// ---------------------------------------------------------------------------
__global__ __launch_bounds__(256, 2)
void attn16(const f16* __restrict__ q16, const f16* __restrict__ k16,
            const f16* __restrict__ vT,
            const float* __restrict__ cosp, const float* __restrict__ sinp,
            f16* __restrict__ attnb)
{
    __shared__ f16 Ks[2][64 * 128];   // 16KB each
    __shared__ f16 Vs[2][128 * 64];   // 16KB each

    const int tid   = threadIdx.x;
    const int lane  = tid & 63;
    const int wid   = tid >> 6;
    const int col_l = lane & 15;
    const int hi    = lane >> 4;

    const int bx = blockIdx.x;
    const int r8 = bx >> 8;              // 0 = heavy round, 1 = light round
    const int c  = bx & 255;
    const int bh = c >> 3;
    const int j8 = c & 7;
    const int qt = r8 ? j8 : (15 - j8);  // pair {15-j, j}: 17 tiles per CU
    const int b  = bh >> 4;
    const int h  = bh & 15;
    const int kv = h >> 2;
    const int qrow = qt * 64 + wid * 16 + col_l;

    // ---- Q load + in-register RoPE + scale (d pairs (d,d+64) = ks, ks+2) ----
    f16x8 qf[4];
    {
        const f16* qp = q16 + (size_t)(b * SEQ + qrow) * 2048 + h * 128 + hi * 8;
        f16x8 raw[4];
        #pragma unroll
        for (int ks = 0; ks < 4; ++ks) raw[ks] = *(const f16x8*)&qp[ks * 32];
        #pragma unroll
        for (int ks = 0; ks < 2; ++ks) {
            union { float4 v; float a[4]; } c0, c1, s0, s1;
            const float* cp = cosp + qrow * HEAD + ks * 32 + hi * 8;
            const float* sp = sinp + qrow * HEAD + ks * 32 + hi * 8;
            c0.v = *(const float4*)cp;  c1.v = *(const float4*)(cp + 4);
            s0.v = *(const float4*)sp;  s1.v = *(const float4*)(sp + 4);
            #pragma unroll
            for (int e = 0; e < 8; ++e) {
                float cc = (e < 4) ? c0.a[e & 3] : c1.a[e & 3];
                float sv = (e < 4) ? s0.a[e & 3] : s1.a[e & 3];
                float lo = (float)raw[ks][e], hv = (float)raw[ks + 2][e];
                qf[ks][e]     = (f16)((lo * cc - hv * sv) * QSC);
                qf[ks + 2][e] = (f16)((hv * cc + lo * sv) * QSC);
            }
        }
    }
    const f16* vTg = vT + (size_t)(b * 4 + kv) * 128 * 1024;

    auto stage = [&](int buf, int kt) {
        #pragma unroll
        for (int j = 0; j < 4; ++j) {          // K: 64 rows x 16 granules
            int gidx = j * 256 + tid;
            int r = gidx >> 4, g = gidx & 15;
            glds16(k16 + (size_t)(b * SEQ + kt * 64 + r) * 512 + kv * 128 + ((g ^ (r & 7)) << 3),
                   (char*)&Ks[buf][0] + (size_t)(j * 256 + (wid << 6)) * 16);
        }
        #pragma unroll
        for (int j = 0; j < 4; ++j) {          // V: 128 d-rows x 8 granules
            int gidx = j * 256 + tid;
            int d = gidx >> 3, g = gidx & 7;
            glds16(vTg + (size_t)d * 1024 + kt * 64 + ((g ^ (d & 7)) << 3),
                   (char*)&Vs[buf][0] + (size_t)(j * 256 + (wid << 6)) * 16);
        }
    };

    f32x4 O[8];
    #pragma unroll
    for (int dt = 0; dt < 8; ++dt) O[dt] = (f32x4){0.f, 0.f, 0.f, 0.f};
    float mrun = -INFINITY, lrun = 0.f;

    const int ntiles = qt + 1;
    stage(0, 0);
    asm volatile("s_waitcnt vmcnt(0)" ::: "memory");
    __syncthreads();

    int cur = 0;
    #pragma unroll 1
    for (int kt = 0; kt < ntiles; ++kt) {
        if (kt + 1 < ntiles) stage(cur ^ 1, kt + 1);

        // ---- S^T = K . Q^T  (four 16-row k-subtiles) ----
        f32x4 S[4];
        #pragma unroll
        for (int t = 0; t < 4; ++t) S[t] = (f32x4){0.f, 0.f, 0.f, 0.f};
        __builtin_amdgcn_s_setprio(1);
        #pragma unroll
        for (int ks = 0; ks < 4; ++ks) {
            int gr = (ks << 2) | hi;
            #pragma unroll
            for (int t = 0; t < 4; ++t) {
                int rr = t * 16 + col_l;
                f16x8 kf = *(const f16x8*)&Ks[cur][rr * 128 + ((gr ^ (rr & 7)) << 3)];
                S[t] = mfma16(kf, qf[ks], S[t]);
            }
        }
        __builtin_amdgcn_s_setprio(0);
        float p[16];
        #pragma unroll
        for (int t = 0; t < 4; ++t) {
            p[t*4+0] = S[t][0]; p[t*4+1] = S[t][1];
            p[t*4+2] = S[t][2]; p[t*4+3] = S[t][3];
        }

        // causal mask (only the diagonal tile): k = kt*64 + (sl>>2)*16 + hi*4 + (sl&3)
        if (kt == qt) {
            #pragma unroll
            for (int sl = 0; sl < 16; ++sl) {
                int kk = kt * 64 + (sl >> 2) * 16 + hi * 4 + (sl & 3);
                if (kk > qrow) p[sl] = -INFINITY;
            }
        }

        // ---- online softmax with defer-max (THR=8) ----
        float pm = p[0];
        #pragma unroll
        for (int sl = 1; sl < 16; ++sl) pm = fmaxf(pm, p[sl]);
        pm = fmaxf(pm, __shfl_xor(pm, 16));
        pm = fmaxf(pm, __shfl_xor(pm, 32));

        if (!__all(pm <= mrun + 8.f)) {
            float mnew = fmaxf(mrun, pm);
            float corr = __expf(mrun - mnew);
            mrun = mnew;
            float cb[4];
            #pragma unroll
            for (int r = 0; r < 4; ++r)
                cb[r] = __int_as_float(__builtin_amdgcn_ds_bpermute((hi * 4 + r) << 2,
                                                                    __float_as_int(corr)));
            #pragma unroll
            for (int dt = 0; dt < 8; ++dt) {
                O[dt][0] *= cb[0]; O[dt][1] *= cb[1];
                O[dt][2] *= cb[2]; O[dt][3] *= cb[3];
            }
            lrun *= corr;
        }

        float ps = 0.f;
        #pragma unroll
        for (int sl = 0; sl < 16; ++sl) { p[sl] = __expf(p[sl] - mrun); ps += p[sl]; }
        ps += __shfl_xor(ps, 16);
        ps += __shfl_xor(ps, 32);
        lrun += ps;

        // ---- repack P into two A-fragments (k 0..31 and 32..63) ----
        union U2 { h16x2 h; int i; };
        int pk[8];
        #pragma unroll
        for (int t = 0; t < 4; ++t) {
            { U2 u; u.h = __builtin_amdgcn_cvt_pkrtz(p[t*4+0], p[t*4+1]); pk[t*2+0] = u.i; }
            { U2 u; u.h = __builtin_amdgcn_cvt_pkrtz(p[t*4+2], p[t*4+3]); pk[t*2+1] = u.i; }
        }
        union UA { f16x8 v; int i[4]; } F0, F1;
        #pragma unroll
        for (int j = 0; j < 4; ++j) {
            int srcl = col_l + 16 * ((2 * hi + (j >> 1)) & 3);
            int a0 = __builtin_amdgcn_ds_bpermute(srcl << 2, pk[j & 1]);
            int a1 = __builtin_amdgcn_ds_bpermute(srcl << 2, pk[2 + (j & 1)]);
            F0.i[j] = (hi >= 2) ? a1 : a0;
            int b0 = __builtin_amdgcn_ds_bpermute(srcl << 2, pk[4 + (j & 1)]);
            int b1 = __builtin_amdgcn_ds_bpermute(srcl << 2, pk[6 + (j & 1)]);
            F1.i[j] = (hi >= 2) ? b1 : b0;
        }

        // ---- O += P @ V  (two k-halves) ----
        __builtin_amdgcn_s_setprio(1);
        #pragma unroll
        for (int dt = 0; dt < 8; ++dt) {
            int vr = dt * 16 + col_l;
            f16x8 v0 = *(const f16x8*)&Vs[cur][vr * 64 + ((hi ^ (vr & 7)) << 3)];
            O[dt] = mfma16(F0.v, v0, O[dt]);
            f16x8 v1 = *(const f16x8*)&Vs[cur][vr * 64 + (((4 | hi) ^ (vr & 7)) << 3)];
            O[dt] = mfma16(F1.v, v1, O[dt]);
        }
        __builtin_amdgcn_s_setprio(0);

        if (kt + 1 < ntiles) {
            asm volatile("s_waitcnt vmcnt(0)" ::: "memory");
            __syncthreads();
            cur ^= 1;
        }
    }

    // ---- finalize ----
    float linv = 1.f / lrun;
    float lb[4];
    #pragma unroll
    for (int r = 0; r < 4; ++r)
        lb[r] = __int_as_float(__builtin_amdgcn_ds_bpermute((hi * 4 + r) << 2,
                                                            __float_as_int(linv)));
    #pragma unroll
    for (int dt = 0; dt < 8; ++dt)
        #pragma unroll
        for (int r = 0; r < 4; ++r) {
            int row = b * SEQ + qt * 64 + wid * 16 + hi * 4 + r;
            attnb[(size_t)row * 2048 + h * 128 + dt * 16 + col_l] = (f16)(O[dt][r] * lb[r]);
        }
}

// ---------------------------------------------------------------------------
extern "C" void kernel_launch(void* const* d_in, const int* in_sizes, int n_in,
                              void* d_out, int out_size, void* d_ws, size_t ws_size,
                              hipStream_t stream)
{
    const float* x    = (const float*)d_in[0];
    const float* cosp = (const float*)d_in[1];
    const float* sinp = (const float*)d_in[2];
    const float* wq   = (const float*)d_in[3];
    const float* wk   = (const float*)d_in[4];
    const float* wv   = (const float*)d_in[5];
    const float* wo   = (const float*)d_in[6];
    float* out = (float*)d_out;

    // workspace layout (40 MiB):
    //   [0,        8388608)  x16    (fp16 x) -> reused as attn out after GEMM1
    //   [8388608, 20971520)  Wqkvt  (fp16 [3072][2048])
    //   [20971520,29360128)  q16    (fp16 [2048][2048], raw; roped in attn)
    //   [29360128,31457280)  k16    (fp16 [2048][512], raw then roped in place)
    //   [31457280,33554432)  vT     (fp16 [(b*4+kv)*128+d][1024])
    //   [33554432,41943040)  Wot    (fp16 [2048][2048])
    char* ws = (char*)d_ws;
    f16* x16    = (f16*)(ws);
    f16* attn16v= (f16*)(ws);                 // overlay (x dead after GEMM1)
    f16* Wqkvt  = (f16*)(ws + 8388608);
    f16* q16    = (f16*)(ws + 20971520);
    f16* k16    = (f16*)(ws + 29360128);
    f16* vT     = (f16*)(ws + 31457280);
    f16* Wot    = (f16*)(ws + 33554432);

    // 1. fused prep: cvt x + transpose Wqkv + transpose Wo
    prep<<<6656, 256, 0, stream>>>(x, wq, wk, wv, wo, x16, Wqkvt, Wot);

    // 2. fused QKV projection (raw q/k fp16, v transposed); 768 blk = 3/CU
    gemm16<1><<<768, 256, 0, stream>>>(x16, Wqkvt, q16, k16, vT, nullptr, 48);

    // 3. in-place RoPE on K only
    rope_k<<<512, 256, 0, stream>>>(k16, cosp, sinp);

    // 4. causal GQA MFMA flash attention v2+ -> attn16 (overlays x16)
    attn16<<<512, 256, 0, stream>>>(q16, k16, vT, cosp, sinp, attn16v);

    // 5. output projection (fp32 out); 512 blk = 2/CU
    gemm16<0><<<512, 256, 0, stream>>>(attn16v, Wot, nullptr, nullptr, nullptr, out, 32);
}